// Round 6
// baseline (2788.043 us; speedup 1.0000x reference)
//
#include <hip/hip_runtime.h>
#include <hip/hip_bf16.h>

typedef __hip_bfloat16 bf16;
typedef unsigned short u16;
typedef unsigned int u32;
typedef unsigned long long u64;
typedef float f32x4 __attribute__((ext_vector_type(4)));
typedef short s16x8 __attribute__((ext_vector_type(8)));
typedef unsigned short u16x4 __attribute__((ext_vector_type(4)));

static constexpr int SQ    = 512;
static constexpr int BB    = 16;
static constexpr int HH    = 1024;
static constexpr int NHEAD = 16;
static constexpr int ROWS  = SQ * BB;        // 8192
static constexpr int QKVC  = 3 * HH;         // 3072

// ---- ws layout (bytes) ----
static constexpr long long OFF_FLAGS = 0;        // flags; cnt at +64; dbg at +128; sink at +192
static constexpr long long OFF_M16   = 4096;     // 512KB expanded mask
static constexpr long long OFF_WQT   = 1048576;
static constexpr long long OFF_WOT   = OFF_WQT + (long long)QKVC * HH * 2;
static constexpr long long OFF_QK    = OFF_WOT + (long long)HH * HH * 2;
static constexpr long long OFF_VT    = OFF_QK + (long long)ROWS * 2048 * 2;
static constexpr long long OFF_CTX   = OFF_VT + (long long)256 * 64 * 512 * 2;

__device__ __forceinline__ float load_f(const void* p, long long i, int is_bf16) {
  if (is_bf16) return __bfloat162float(((const bf16*)p)[i]);
  return ((const float*)p)[i];
}
__device__ __forceinline__ u16 f2b(float x) { bf16 h = __float2bfloat16(x); return *(u16*)&h; }
__device__ __forceinline__ f32x4 mfma_bf16(s16x8 a, s16x8 b, f32x4 c) {
  return __builtin_amdgcn_mfma_f32_16x16x32_bf16(a, b, c, 0, 0, 0);
}
__device__ __forceinline__ void gll16(const void* g, void* lds) {
  __builtin_amdgcn_global_load_lds((const __attribute__((address_space(1))) unsigned int*)g,
                                   (__attribute__((address_space(3))) unsigned int*)lds, 16, 0, 0);
}
__device__ __forceinline__ u32 cvtpk(float lo, float hi) {
  u32 r;
  asm volatile("v_cvt_pk_bf16_f32 %0, %1, %2" : "=v"(r) : "v"(lo), "v"(hi));
  return r;
}
// bijective XCD-aware block swizzle (T1, m204); requires (gx*gy)%8==0
__device__ __forceinline__ void xcd_swz(int& bx, int& by) {
  int gx = gridDim.x;
  int nw = gx * gridDim.y;
  int lin = by * gx + bx;
  int q = nw >> 3;
  int nl = (lin & 7) * q + (lin >> 3);
  bx = nl % gx;
  by = nl / gx;
}

// ---------------- dtype detection (verified r1-r4, verbatim) ----------------
__global__ __launch_bounds__(256) void sa_detect_part(const void* hs, const void* mask, int* cnt) {
  __shared__ int lc[6];
  if (threadIdx.x < 6) lc[threadIdx.x] = 0;
  __syncthreads();
  int gid = blockIdx.x * 256 + threadIdx.x;
  if (gid < 2048) {
    unsigned short v = ((const unsigned short*)hs)[2 * gid];
    float f = __uint_as_float(((unsigned)v) << 16);
    float a = fabsf(f);
    if (v == 0 || (a > 1e-9f && a < 1e4f)) atomicAdd(&lc[0], 1);
  }
  const unsigned char* mb = (const unsigned char*)mask;
  int codd = 0, c1 = 0, c3f = 0, c48 = 0, cb1 = 0;
  #pragma unroll
  for (int r = 0; r < 4; ++r) {
    int i = gid * 4 + r;
    int base = i * 4;
    unsigned char b1 = mb[base + 1], b3 = mb[base + 3];
    if (b1 | b3) codd++;
    if (b1) cb1++;
    if (b1 == 1) c1++;
    if (b3 == 1) c1++;
    if (b1 == 0x3f) c3f++;
    if (b3 == 0x3f) c3f++;
    if (i & 1) { if (mb[base]) c48++; }
  }
  atomicAdd(&lc[1], codd);
  atomicAdd(&lc[2], c1);
  atomicAdd(&lc[3], c3f);
  atomicAdd(&lc[4], c48);
  atomicAdd(&lc[5], cb1);
  __syncthreads();
  if (threadIdx.x < 6) atomicAdd(&cnt[threadIdx.x], lc[threadIdx.x]);
}

__global__ void sa_detect_fin(const int* cnt, int* flags) {
  if (threadIdx.x != 0) return;
  flags[0] = (cnt[0] > 1800) ? 1 : 0;
  int mm;
  if (cnt[1] == 0)           mm = (cnt[4] > 0) ? 0 : 1;
  else if (cnt[2] >= cnt[3]) mm = 2;
  else if (cnt[5] == 0)      mm = 3;
  else                       mm = 4;
  flags[1] = mm;
}

// ---------------- mask -> expanded u16 (0xFFFF / 0), MFMA-frag order (verified r4) ----------------
__global__ __launch_bounds__(256) void sa_maskexp(const void* mask, u16* m16, const int* flags) {
  int idx = blockIdx.x * 256 + threadIdx.x;
  int i = idx >> 9, c = idx & 511;
  int jw = c >> 5, r = c & 31;
  int g = r >> 3, q = r & 7;
  int t = q >> 2, rr = q & 3;
  long long j = (long long)i * 512 + jw * 32 + t * 16 + 4 * g + rr;
  int mm = flags[1];
  bool v;
  if      (mm == 0) v = ((const int*)mask)[j] != 0;
  else if (mm == 1) v = ((const long long*)mask)[j] != 0;
  else if (mm == 2) v = ((const unsigned char*)mask)[j] != 0;
  else if (mm == 3) v = ((const float*)mask)[j] != 0.0f;
  else              v = ((const unsigned short*)mask)[j] != 0;
  m16[idx] = v ? 0xFFFFu : 0u;
}

// ---------------- hidden -> bf16, pre-swizzled 16B chunks (verified r4, flags) ----------------
__global__ __launch_bounds__(256) void sa_cvt_hs(const void* hs, u16* hsb, const int* flags) {
  int tid = blockIdx.x * 256 + threadIdx.x;
  int row = tid >> 7, u7 = tid & 127;
  int sc = u7 >> 3, u = u7 & 7;
  long long ebase = (long long)row * 1024 + sc * 64 + u * 8;
  s16x8 ov;
  if (flags[0]) {
    ov = *(const s16x8*)((const u16*)hs + ebase);
  } else {
    const float4* pf = (const float4*)((const float*)hs + ebase);
    float4 x0 = pf[0], x1 = pf[1];
    ov[0] = f2b(x0.x); ov[1] = f2b(x0.y); ov[2] = f2b(x0.z); ov[3] = f2b(x0.w);
    ov[4] = f2b(x1.x); ov[5] = f2b(x1.y); ov[6] = f2b(x1.z); ov[7] = f2b(x1.w);
  }
  *(s16x8*)((char*)hsb + (long long)row * 2048 + sc * 128 + ((u ^ (row & 7)) * 16)) = ov;
}

// ---------------- W (K x N) -> WT (N x K) bf16 pre-swizzled (verified r4, serial gather) ----------------
__global__ __launch_bounds__(256) void sa_wtrans(const void* W, u16* WT, int Nld, const int* flags) {
  int tid = blockIdx.x * 256 + threadIdx.x;
  int nrow = tid >> 7, u7 = tid & 127;
  int sc = u7 >> 3, u = u7 & 7;
  int kb = sc * 64 + u * 8;
  const int fl = flags[0];
  s16x8 ov;
  #pragma unroll
  for (int e = 0; e < 8; ++e) ov[e] = f2b(load_f(W, (long long)(kb + e) * Nld + nrow, fl));
  *(s16x8*)((char*)WT + (long long)nrow * 2048 + sc * 128 + ((u ^ (nrow & 7)) * 16)) = ov;
}

// ---------------- DIAGNOSTIC A: r5 tiled transpose vs verified WT; mismatches -> dbg[0] ----------------
__global__ __launch_bounds__(256) void sa_wtrans2chk(const u16* __restrict__ W, const u16* __restrict__ WT,
                                                     int Nld, int K, int* dbg) {
  __shared__ u16 T[64 * 64];
  const int tid = threadIdx.x;
  const int n0 = blockIdx.x * 64, k0 = blockIdx.y * 64;
  #pragma unroll
  for (int it = 0; it < 2; ++it) {
    int kk = it * 32 + (tid >> 3), c = tid & 7;
    s16x8 v = *(const s16x8*)(W + (long long)(k0 + kk) * Nld + n0 + c * 8);
    int pc = c ^ (kk & 7) ^ ((kk >> 3) & 7);
    *(s16x8*)(T + kk * 64 + pc * 8) = v;
  }
  __syncthreads();
  int mism = 0;
  #pragma unroll
  for (int it = 0; it < 2; ++it) {
    int nr = it * 32 + (tid >> 3), u = tid & 7;
    s16x8 o;
    #pragma unroll
    for (int e = 0; e < 8; ++e) {
      int k = u * 8 + e;
      int pc = (nr >> 3) ^ (k & 7) ^ ((k >> 3) & 7);
      o[e] = T[k * 64 + pc * 8 + (nr & 7)];
    }
    int nrow = n0 + nr;
    s16x8 ev = *(const s16x8*)((const char*)WT + (long long)nrow * (K * 2) +
                               (k0 >> 6) * 128 + ((u ^ (nrow & 7)) * 16));
    #pragma unroll
    for (int e = 0; e < 8; ++e) if (o[e] != ev[e]) mism++;
  }
  if (mism) atomicAdd(&dbg[0], mism);
}

// ---------------- MFMA GEMM 1 (verified r4) + xcd swizzle ----------------
__global__ __launch_bounds__(256) void mm_qkv(const u16* __restrict__ Asrc, const u16* __restrict__ BT,
                                              const void* bias, u16* qk, u16* vT, const int* flags) {
  __shared__ u16 As[128 * 64];
  __shared__ u16 Bs[128 * 64];
  const int tid = threadIdx.x, w = tid >> 6, lane = tid & 63;
  const int g = lane >> 4, li = lane & 15;
  int bx = blockIdx.x, by = blockIdx.y;
  xcd_swz(bx, by);
  const int m0 = by * 128, n0 = bx * 128;
  const int wm = (w >> 1) * 64, wn = (w & 1) * 64;
  const int K = 1024;
  f32x4 acc[4][4] = {};
  for (int k0 = 0; k0 < K; k0 += 64) {
    if (k0) __syncthreads();
    #pragma unroll
    for (int q = 0; q < 4; ++q) {
      int c = w * 4 + q;
      int r = c * 8 + (lane >> 3);
      gll16(Asrc + (long long)(m0 + r) * K + k0 + (lane & 7) * 8, &As[c * 512]);
      gll16(BT   + (long long)(n0 + r) * K + k0 + (lane & 7) * 8, &Bs[c * 512]);
    }
    __syncthreads();
    #pragma unroll
    for (int ks = 0; ks < 2; ++ks) {
      s16x8 af[4], bfr[4];
      #pragma unroll
      for (int mi = 0; mi < 4; ++mi) {
        int r = wm + mi * 16 + li;
        int off = (ks * 64 + g * 16) ^ ((r & 7) << 4);
        af[mi] = *(const s16x8*)((const char*)As + r * 128 + off);
      }
      #pragma unroll
      for (int nj = 0; nj < 4; ++nj) {
        int r = wn + nj * 16 + li;
        int off = (ks * 64 + g * 16) ^ ((r & 7) << 4);
        bfr[nj] = *(const s16x8*)((const char*)Bs + r * 128 + off);
      }
      #pragma unroll
      for (int mi = 0; mi < 4; ++mi)
        #pragma unroll
        for (int nj = 0; nj < 4; ++nj)
          acc[mi][nj] = mfma_bf16(af[mi], bfr[nj], acc[mi][nj]);
    }
  }
  const int fl = flags[0];
  const int s0 = (m0 + wm) >> 4;
  #pragma unroll
  for (int nj = 0; nj < 4; ++nj) {
    int colbase = n0 + wn + nj * 16;
    int col = colbase + li;
    float bv = load_f(bias, col, fl);
    int c16 = colbase >> 4;
    int ht = c16 % 12, n = c16 / 12;
    int colmod = (ht * 16) + li;
    if (ht < 8) {
      #pragma unroll
      for (int mi = 0; mi < 4; ++mi) {
        int s = s0 + mi;
        #pragma unroll
        for (int rr = 0; rr < 4; ++rr) {
          int b = 4 * g + rr;
          qk[((long long)(b * 512 + s)) * 2048 + n * 128 + colmod] =
              f2b(acc[mi][nj][rr] + bv);
        }
      }
    } else {
      int d = colmod - 128;
      #pragma unroll
      for (int rr = 0; rr < 4; ++rr) {
        int b = 4 * g + rr;
        u16x4 pk;
        #pragma unroll
        for (int mi = 0; mi < 4; ++mi) pk[mi] = f2b(acc[mi][nj][rr] + bv);
        *(u16x4*)(vT + ((long long)(b * 16 + n)) * 32768 + (long long)d * 512 + s0) = pk;
      }
    }
  }
}

// ---------------- flash attention v4 (verified r4, verbatim) ----------------
__global__ __launch_bounds__(1024) void sa_attn4(const u16* __restrict__ qk, const u16* __restrict__ vT,
                                                 const u16* __restrict__ m16, u16* __restrict__ ctx) {
  __shared__ __align__(16) u16 SHM[49152];
  u16* const Vs = SHM;
  u16* const PB = SHM + 32768;

  const int tid = threadIdx.x, w = tid >> 6, lane = tid & 63;
  const int g = lane >> 4, li = lane & 15;
  const int n = blockIdx.x, b = blockIdx.y;

  const u16* vg = vT + (long long)(b * 16 + n) * 32768;
  #pragma unroll
  for (int q = 0; q < 4; ++q) {
    int lin = q * 1024 + tid;
    int d = lin >> 6, c = lin & 63;
    s16x8 v = *(const s16x8*)(vg + (long long)d * 512 + c * 8);
    *(s16x8*)((char*)Vs + d * 1024 + ((c ^ (d & 7)) * 16)) = v;
  }
  __syncthreads();

  const int i0 = w * 32;
  s16x8 qf0[2], qf1[2];
  #pragma unroll
  for (int tl = 0; tl < 2; ++tl) {
    const u16* qb = qk + ((long long)(b * 512 + i0 + tl * 16 + li)) * 2048 + n * 128;
    qf0[tl] = *(const s16x8*)(qb + g * 8);
    qf1[tl] = *(const s16x8*)(qb + 32 + g * 8);
  }
  s16x8 af1;
  #pragma unroll
  for (int e = 0; e < 8; ++e) af1[e] = (li == 0) ? (short)0x3F80 : (short)0;

  char* const pw = (char*)PB + w * 2048;
  const float SC  = 0.125f * 1.44269504f;
  const float THR = 44.3614f;

  const u16* kbase = qk + (long long)(b * 512) * 2048 + n * 128 + 64;
  const u16* mk0 = m16 + (long long)(i0 + li) * 512 + g * 8;
  const u16* mk1 = m16 + (long long)(i0 + 16 + li) * 512 + g * 8;

  f32x4 cacc[2][4] = {};
  f32x4 lacc[2] = {};
  float m[2] = {-1e30f, -1e30f};

  for (int jw = 0; jw < 16; ++jw) {
    uint4 mmv[2];
    mmv[0] = *(const uint4*)(mk0 + jw * 32);
    mmv[1] = *(const uint4*)(mk1 + jw * 32);
    s16x8 kf0[2], kf1[2];
    #pragma unroll
    for (int t = 0; t < 2; ++t) {
      const u16* kb = kbase + (long long)(jw * 32 + t * 16 + li) * 2048;
      kf0[t] = *(const s16x8*)(kb + g * 8);
      kf1[t] = *(const s16x8*)(kb + 32 + g * 8);
    }
    f32x4 sa[2][2];
    #pragma unroll
    for (int tl = 0; tl < 2; ++tl)
      #pragma unroll
      for (int t = 0; t < 2; ++t) {
        f32x4 z = {};
        z = mfma_bf16(kf0[t], qf0[tl], z);
        z = mfma_bf16(kf1[t], qf1[tl], z);
        sa[tl][t] = z;
      }
    s16x8 pf[2];
    #pragma unroll
    for (int tl = 0; tl < 2; ++tl) {
      float pm = fmaxf(fmaxf(fmaxf(sa[tl][0][0], sa[tl][0][1]), fmaxf(sa[tl][0][2], sa[tl][0][3])),
                       fmaxf(fmaxf(sa[tl][1][0], sa[tl][1][1]), fmaxf(sa[tl][1][2], sa[tl][1][3])));
      pm = fmaxf(pm, __shfl_xor(pm, 16));
      pm = fmaxf(pm, __shfl_xor(pm, 32));
      if (__any(pm > m[tl] + THR)) {
        float mn = fmaxf(m[tl], pm);
        float sc = __builtin_exp2f((m[tl] - mn) * SC);
        lacc[tl] *= sc;
        #pragma unroll
        for (int dt = 0; dt < 4; ++dt) cacc[tl][dt] *= sc;
        m[tl] = mn;
      }
      float mv = m[tl];
      float p0 = __builtin_exp2f((sa[tl][0][0] - mv) * SC);
      float p1 = __builtin_exp2f((sa[tl][0][1] - mv) * SC);
      float p2 = __builtin_exp2f((sa[tl][0][2] - mv) * SC);
      float p3 = __builtin_exp2f((sa[tl][0][3] - mv) * SC);
      float p4 = __builtin_exp2f((sa[tl][1][0] - mv) * SC);
      float p5 = __builtin_exp2f((sa[tl][1][1] - mv) * SC);
      float p6 = __builtin_exp2f((sa[tl][1][2] - mv) * SC);
      float p7 = __builtin_exp2f((sa[tl][1][3] - mv) * SC);
      u32 r0 = cvtpk(p0, p1) & mmv[tl].x;
      u32 r1 = cvtpk(p2, p3) & mmv[tl].y;
      u32 r2 = cvtpk(p4, p5) & mmv[tl].z;
      u32 r3 = cvtpk(p6, p7) & mmv[tl].w;
      char* pt = pw + tl * 1024 + li * 64;
      *(uint2*)(pt + ((g ^ (li & 6)) * 8))       = make_uint2(r0, r1);
      *(uint2*)(pt + (((4 + g) ^ (li & 6)) * 8)) = make_uint2(r2, r3);
      pf[tl] = *(const s16x8*)(pw + tl * 1024 + li * 64 + (((2 * g) ^ (li & 6)) * 8));
      lacc[tl] = mfma_bf16(af1, pf[tl], lacc[tl]);
    }
    #pragma unroll
    for (int dt = 0; dt < 4; ++dt) {
      int d = dt * 16 + li;
      s16x8 vf = *(const s16x8*)((const char*)Vs + d * 1024 + (((jw * 4 + g) ^ (d & 7)) * 16));
      #pragma unroll
      for (int tl = 0; tl < 2; ++tl)
        cacc[tl][dt] = mfma_bf16(vf, pf[tl], cacc[tl][dt]);
    }
  }
  #pragma unroll
  for (int tl = 0; tl < 2; ++tl) {
    float lv = __shfl(lacc[tl][0], li);
    float inv = 1.0f / lv;
    #pragma unroll
    for (int dt = 0; dt < 4; ++dt) {
      u32 lo = cvtpk(cacc[tl][dt][0] * inv, cacc[tl][dt][1] * inv);
      u32 hi = cvtpk(cacc[tl][dt][2] * inv, cacc[tl][dt][3] * inv);
      *(uint2*)(pw + li * 128 + (((dt * 4 + g) ^ ((li & 7) << 1)) * 8)) = make_uint2(lo, hi);
    }
    int il = lane >> 2;
    #pragma unroll
    for (int p = 0; p < 2; ++p) {
      int c = (lane & 3) + p * 4;
      s16x8 v = *(const s16x8*)(pw + il * 128 + (((2 * c) ^ ((il & 7) << 1)) * 8));
      *(s16x8*)(ctx + ((long long)((i0 + tl * 16 + il) * 16 + b)) * 1024 + n * 64 +
                ((c ^ (b & 7)) * 8)) = v;
    }
  }
}

// ---------------- DIAGNOSTIC B: attention with r5 Vs swizzle, bitwise-compared vs ctx ----------------
__global__ __launch_bounds__(1024) void sa_attn5diag(const u16* __restrict__ qk, const u16* __restrict__ vT,
                                                     const u16* __restrict__ m16,
                                                     const u16* __restrict__ ctx, int* dbg) {
  __shared__ __align__(16) u16 SHM[49152];
  u16* const Vs = SHM;                          // r5 layout: [64 d][64 chunks], pc = c^(d&7)^(d>>3)
  u16* const PB = SHM + 32768;

  const int tid = threadIdx.x, w = tid >> 6, lane = tid & 63;
  const int g = lane >> 4, li = lane & 15;
  const int n = blockIdx.x, b = blockIdx.y;

  const u16* vg = vT + (long long)(b * 16 + n) * 32768;
  #pragma unroll
  for (int q = 0; q < 4; ++q) {
    int lin = q * 1024 + tid;
    int d = lin >> 6, c = lin & 63;
    s16x8 v = *(const s16x8*)(vg + (long long)d * 512 + c * 8);
    int pc = c ^ (d & 7) ^ ((d >> 3) & 7);      // r5 swizzle under test
    *(s16x8*)(Vs + d * 512 + pc * 8) = v;
  }
  __syncthreads();

  const int i0 = w * 32;
  s16x8 qf0[2], qf1[2];
  #pragma unroll
  for (int tl = 0; tl < 2; ++tl) {
    const u16* qb = qk + ((long long)(b * 512 + i0 + tl * 16 + li)) * 2048 + n * 128;
    qf0[tl] = *(const s16x8*)(qb + g * 8);
    qf1[tl] = *(const s16x8*)(qb + 32 + g * 8);
  }
  s16x8 af1;
  #pragma unroll
  for (int e = 0; e < 8; ++e) af1[e] = (li == 0) ? (short)0x3F80 : (short)0;

  char* const pw = (char*)PB + w * 2048;
  const float SC  = 0.125f * 1.44269504f;
  const float THR = 44.3614f;

  const u16* kbase = qk + (long long)(b * 512) * 2048 + n * 128 + 64;
  const u16* mk0 = m16 + (long long)(i0 + li) * 512 + g * 8;
  const u16* mk1 = m16 + (long long)(i0 + 16 + li) * 512 + g * 8;

  f32x4 cacc[2][4] = {};
  f32x4 lacc[2] = {};
  float m[2] = {-1e30f, -1e30f};

  for (int jw = 0; jw < 16; ++jw) {
    uint4 mmv[2];
    mmv[0] = *(const uint4*)(mk0 + jw * 32);
    mmv[1] = *(const uint4*)(mk1 + jw * 32);
    s16x8 kf0[2], kf1[2];
    #pragma unroll
    for (int t = 0; t < 2; ++t) {
      const u16* kb = kbase + (long long)(jw * 32 + t * 16 + li) * 2048;
      kf0[t] = *(const s16x8*)(kb + g * 8);
      kf1[t] = *(const s16x8*)(kb + 32 + g * 8);
    }
    f32x4 sa[2][2];
    #pragma unroll
    for (int tl = 0; tl < 2; ++tl)
      #pragma unroll
      for (int t = 0; t < 2; ++t) {
        f32x4 z = {};
        z = mfma_bf16(kf0[t], qf0[tl], z);
        z = mfma_bf16(kf1[t], qf1[tl], z);
        sa[tl][t] = z;
      }
    s16x8 pf[2];
    #pragma unroll
    for (int tl = 0; tl < 2; ++tl) {
      float pm = fmaxf(fmaxf(fmaxf(sa[tl][0][0], sa[tl][0][1]), fmaxf(sa[tl][0][2], sa[tl][0][3])),
                       fmaxf(fmaxf(sa[tl][1][0], sa[tl][1][1]), fmaxf(sa[tl][1][2], sa[tl][1][3])));
      pm = fmaxf(pm, __shfl_xor(pm, 16));
      pm = fmaxf(pm, __shfl_xor(pm, 32));
      if (__any(pm > m[tl] + THR)) {
        float mn = fmaxf(m[tl], pm);
        float sc = __builtin_exp2f((m[tl] - mn) * SC);
        lacc[tl] *= sc;
        #pragma unroll
        for (int dt = 0; dt < 4; ++dt) cacc[tl][dt] *= sc;
        m[tl] = mn;
      }
      float mv = m[tl];
      float p0 = __builtin_exp2f((sa[tl][0][0] - mv) * SC);
      float p1 = __builtin_exp2f((sa[tl][0][1] - mv) * SC);
      float p2 = __builtin_exp2f((sa[tl][0][2] - mv) * SC);
      float p3 = __builtin_exp2f((sa[tl][0][3] - mv) * SC);
      float p4 = __builtin_exp2f((sa[tl][1][0] - mv) * SC);
      float p5 = __builtin_exp2f((sa[tl][1][1] - mv) * SC);
      float p6 = __builtin_exp2f((sa[tl][1][2] - mv) * SC);
      float p7 = __builtin_exp2f((sa[tl][1][3] - mv) * SC);
      u32 r0 = cvtpk(p0, p1) & mmv[tl].x;
      u32 r1 = cvtpk(p2, p3) & mmv[tl].y;
      u32 r2 = cvtpk(p4, p5) & mmv[tl].z;
      u32 r3 = cvtpk(p6, p7) & mmv[tl].w;
      char* pt = pw + tl * 1024 + li * 64;
      *(uint2*)(pt + ((g ^ (li & 6)) * 8))       = make_uint2(r0, r1);
      *(uint2*)(pt + (((4 + g) ^ (li & 6)) * 8)) = make_uint2(r2, r3);
      pf[tl] = *(const s16x8*)(pw + tl * 1024 + li * 64 + (((2 * g) ^ (li & 6)) * 8));
      lacc[tl] = mfma_bf16(af1, pf[tl], lacc[tl]);
    }
    #pragma unroll
    for (int dt = 0; dt < 4; ++dt) {
      int d = dt * 16 + li;
      s16x8 vf = *(const s16x8*)(Vs + d * 512 +
                                 (((jw * 4 + g) ^ (d & 7) ^ ((d >> 3) & 7)) * 8));
      #pragma unroll
      for (int tl = 0; tl < 2; ++tl)
        cacc[tl][dt] = mfma_bf16(vf, pf[tl], cacc[tl][dt]);
    }
  }
  #pragma unroll
  for (int tl = 0; tl < 2; ++tl) {
    float lv = __shfl(lacc[tl][0], li);
    float inv = 1.0f / lv;
    #pragma unroll
    for (int dt = 0; dt < 4; ++dt) {
      u32 lo = cvtpk(cacc[tl][dt][0] * inv, cacc[tl][dt][1] * inv);
      u32 hi = cvtpk(cacc[tl][dt][2] * inv, cacc[tl][dt][3] * inv);
      *(uint2*)(pw + li * 128 + (((dt * 4 + g) ^ ((li & 7) << 1)) * 8)) = make_uint2(lo, hi);
    }
    int il = lane >> 2;
    int mism = 0;
    #pragma unroll
    for (int p = 0; p < 2; ++p) {
      int c = (lane & 3) + p * 4;
      s16x8 v = *(const s16x8*)(pw + il * 128 + (((2 * c) ^ ((il & 7) << 1)) * 8));
      s16x8 ev = *(const s16x8*)(ctx + ((long long)((i0 + tl * 16 + il) * 16 + b)) * 1024 + n * 64 +
                                 ((c ^ (b & 7)) * 8));
      #pragma unroll
      for (int e = 0; e < 8; ++e) if (v[e] != ev[e]) mism++;
    }
    if (mism) atomicAdd(&dbg[1], mism);
  }
}

// spin marker: visible in rocprof top-5 only if dbg[idx] != 0
__global__ void sa_spin(const int* dbg, int idx, int iters, int* sink) {
  if (dbg[idx] == 0) return;
  float v = 1.0f;
  for (int i = 0; i < iters; ++i) v = fmaf(v, 0.9999999f, 1e-9f);
  if (v == 123.456f) *sink = 1;
}

// ---------------- MFMA GEMM 2 (verified r4) + xcd swizzle ----------------
__global__ __launch_bounds__(256) void mm_out(const u16* __restrict__ Asrc, const u16* __restrict__ BT,
                                              const void* bias, void* out, const int* flags) {
  __shared__ u16 As[128 * 64];
  __shared__ u16 Bs[128 * 64];
  const int tid = threadIdx.x, w = tid >> 6, lane = tid & 63;
  const int g = lane >> 4, li = lane & 15;
  int bx = blockIdx.x, by = blockIdx.y;
  xcd_swz(bx, by);
  const int m0 = by * 128, n0 = bx * 128;
  const int wm = (w >> 1) * 64, wn = (w & 1) * 64;
  const int K = 1024;
  f32x4 acc[4][4] = {};
  for (int k0 = 0; k0 < K; k0 += 64) {
    if (k0) __syncthreads();
    #pragma unroll
    for (int q = 0; q < 4; ++q) {
      int c = w * 4 + q;
      int r = c * 8 + (lane >> 3);
      gll16(Asrc + (long long)(m0 + r) * K + k0 + (lane & 7) * 8, &As[c * 512]);
      gll16(BT   + (long long)(n0 + r) * K + k0 + (lane & 7) * 8, &Bs[c * 512]);
    }
    __syncthreads();
    #pragma unroll
    for (int ks = 0; ks < 2; ++ks) {
      s16x8 af[4], bfr[4];
      #pragma unroll
      for (int mi = 0; mi < 4; ++mi) {
        int r = wm + mi * 16 + li;
        int off = (ks * 64 + g * 16) ^ ((r & 7) << 4);
        af[mi] = *(const s16x8*)((const char*)As + r * 128 + off);
      }
      #pragma unroll
      for (int nj = 0; nj < 4; ++nj) {
        int r = wn + nj * 16 + li;
        int off = (ks * 64 + g * 16) ^ ((r & 7) << 4);
        bfr[nj] = *(const s16x8*)((const char*)Bs + r * 128 + off);
      }
      #pragma unroll
      for (int mi = 0; mi < 4; ++mi)
        #pragma unroll
        for (int nj = 0; nj < 4; ++nj)
          acc[mi][nj] = mfma_bf16(af[mi], bfr[nj], acc[mi][nj]);
    }
  }
  const int fl = flags[0];
  #pragma unroll
  for (int nj = 0; nj < 4; ++nj) {
    int col = n0 + wn + nj * 16 + li;
    float bv = load_f(bias, col, fl);
    #pragma unroll
    for (int mi = 0; mi < 4; ++mi) {
      #pragma unroll
      for (int rr = 0; rr < 4; ++rr) {
        long long row = m0 + wm + mi * 16 + 4 * g + rr;
        float v = acc[mi][nj][rr] + bv;
        if (fl) ((u16*)out)[row * 1024 + col] = f2b(v);
        else    ((float*)out)[row * 1024 + col] = v;
      }
    }
  }
}

extern "C" void kernel_launch(void* const* d_in, const int* in_sizes, int n_in,
                              void* d_out, int out_size, void* d_ws, size_t ws_size,
                              hipStream_t stream) {
  const void* hs   = d_in[0];
  const void* mask = d_in[1];
  const void* Wqkv = d_in[2];
  const void* bqkv = d_in[3];
  const void* Wout = d_in[4];
  const void* bout = d_in[5];

  char* ws = (char*)d_ws;
  int* flags = (int*)(ws + OFF_FLAGS);
  int* cnt   = (int*)(ws + 64);
  int* dbg   = (int*)(ws + 128);
  int* sink  = (int*)(ws + 192);
  u16* m16   = (u16*)(ws + OFF_M16);
  u16* WqkvT = (u16*)(ws + OFF_WQT);
  u16* WoutT = (u16*)(ws + OFF_WOT);
  u16* qk    = (u16*)(ws + OFF_QK);
  u16* vT    = (u16*)(ws + OFF_VT);
  u16* ctx   = (u16*)(ws + OFF_CTX);
  u16* hsb   = ctx;   // aliased; hsb dead before ctx written

  hipMemsetAsync(ws + 64, 0, 128, stream);
  sa_detect_part<<<64, 256, 0, stream>>>(hs, mask, cnt);
  sa_detect_fin<<<1, 64, 0, stream>>>(cnt, flags);
  sa_maskexp<<<1024, 256, 0, stream>>>(mask, m16, flags);
  sa_cvt_hs<<<(ROWS * 128) / 256, 256, 0, stream>>>(hs, hsb, flags);
  sa_wtrans<<<(QKVC * 128) / 256, 256, 0, stream>>>(Wqkv, WqkvT, QKVC, flags);
  sa_wtrans<<<(HH * 128) / 256, 256, 0, stream>>>(Wout, WoutT, HH, flags);
  // diagnostic A: r5 tiled transpose vs verified WoutT
  sa_wtrans2chk<<<dim3(HH / 64, HH / 64), 256, 0, stream>>>((const u16*)Wout, WoutT, HH, HH, dbg);

  mm_qkv<<<dim3(QKVC / 128, ROWS / 128), 256, 0, stream>>>(hsb, WqkvT, bqkv, qk, vT, flags);
  sa_attn4<<<dim3(NHEAD, BB), 1024, 0, stream>>>(qk, vT, m16, ctx);
  // diagnostic B: r5 Vs swizzle pair, bitwise vs attn4's ctx
  sa_attn5diag<<<dim3(NHEAD, BB), 1024, 0, stream>>>(qk, vT, m16, ctx, dbg);
  sa_spin<<<1, 64, 0, stream>>>(dbg, 0, 150000, sink);   // ~250us iff wtrans2 mismatch
  sa_spin<<<1, 64, 0, stream>>>(dbg, 1, 300000, sink);   // ~500us iff attn5 mismatch

  mm_out<<<dim3(HH / 128, ROWS / 128), 256, 0, stream>>>(ctx, WoutT, bout, d_out, flags);
}

// Round 8
// 1296.152 us; speedup vs baseline: 2.1510x; 2.1510x over previous
//
#include <hip/hip_runtime.h>
#include <hip/hip_bf16.h>

typedef __hip_bfloat16 bf16;
typedef unsigned short u16;
typedef unsigned int u32;
typedef unsigned long long u64;
typedef float f32x4 __attribute__((ext_vector_type(4)));
typedef short s16x8 __attribute__((ext_vector_type(8)));
typedef unsigned short u16x4 __attribute__((ext_vector_type(4)));

static constexpr int SQ    = 512;
static constexpr int BB    = 16;
static constexpr int HH    = 1024;
static constexpr int NHEAD = 16;
static constexpr int ROWS  = SQ * BB;        // 8192
static constexpr int QKVC  = 3 * HH;         // 3072

// ---- ws layout (bytes) ----
static constexpr long long OFF_FLAGS = 0;        // flags; cnt at +64; dbg at +128; sink at +192
static constexpr long long OFF_M16   = 4096;     // 512KB expanded mask
static constexpr long long OFF_WQT   = 1048576;
static constexpr long long OFF_WOT   = OFF_WQT + (long long)QKVC * HH * 2;
static constexpr long long OFF_QK    = OFF_WOT + (long long)HH * HH * 2;
static constexpr long long OFF_VT    = OFF_QK + (long long)ROWS * 2048 * 2;
static constexpr long long OFF_CTX   = OFF_VT + (long long)256 * 64 * 512 * 2;

__device__ __forceinline__ float load_f(const void* p, long long i, int is_bf16) {
  if (is_bf16) return __bfloat162float(((const bf16*)p)[i]);
  return ((const float*)p)[i];
}
__device__ __forceinline__ u16 f2b(float x) { bf16 h = __float2bfloat16(x); return *(u16*)&h; }
__device__ __forceinline__ f32x4 mfma_bf16(s16x8 a, s16x8 b, f32x4 c) {
  return __builtin_amdgcn_mfma_f32_16x16x32_bf16(a, b, c, 0, 0, 0);
}
__device__ __forceinline__ void gll16(const void* g, void* lds) {
  __builtin_amdgcn_global_load_lds((const __attribute__((address_space(1))) unsigned int*)g,
                                   (__attribute__((address_space(3))) unsigned int*)lds, 16, 0, 0);
}
__device__ __forceinline__ u32 cvtpk(float lo, float hi) {
  u32 r;
  asm volatile("v_cvt_pk_bf16_f32 %0, %1, %2" : "=v"(r) : "v"(lo), "v"(hi));
  return r;
}
__device__ __forceinline__ void xcd_swz(int& bx, int& by) {
  int gx = gridDim.x;
  int nw = gx * gridDim.y;
  int lin = by * gx + bx;
  int q = nw >> 3;
  int nl = (lin & 7) * q + (lin >> 3);
  bx = nl % gx;
  by = nl / gx;
}
// diagnostic pattern
__device__ __forceinline__ u16 hpat(int bn, int s, int d) {
  return (u16)((u32)bn * 40503u + (u32)s * 1201u + (u32)d * 7919u + 17u);
}

// ---------------- dtype detection (verified r1-r4/r6, verbatim) ----------------
__global__ __launch_bounds__(256) void sa_detect_part(const void* hs, const void* mask, int* cnt) {
  __shared__ int lc[6];
  if (threadIdx.x < 6) lc[threadIdx.x] = 0;
  __syncthreads();
  int gid = blockIdx.x * 256 + threadIdx.x;
  if (gid < 2048) {
    unsigned short v = ((const unsigned short*)hs)[2 * gid];
    float f = __uint_as_float(((unsigned)v) << 16);
    float a = fabsf(f);
    if (v == 0 || (a > 1e-9f && a < 1e4f)) atomicAdd(&lc[0], 1);
  }
  const unsigned char* mb = (const unsigned char*)mask;
  int codd = 0, c1 = 0, c3f = 0, c48 = 0, cb1 = 0;
  #pragma unroll
  for (int r = 0; r < 4; ++r) {
    int i = gid * 4 + r;
    int base = i * 4;
    unsigned char b1 = mb[base + 1], b3 = mb[base + 3];
    if (b1 | b3) codd++;
    if (b1) cb1++;
    if (b1 == 1) c1++;
    if (b3 == 1) c1++;
    if (b1 == 0x3f) c3f++;
    if (b3 == 0x3f) c3f++;
    if (i & 1) { if (mb[base]) c48++; }
  }
  atomicAdd(&lc[1], codd);
  atomicAdd(&lc[2], c1);
  atomicAdd(&lc[3], c3f);
  atomicAdd(&lc[4], c48);
  atomicAdd(&lc[5], cb1);
  __syncthreads();
  if (threadIdx.x < 6) atomicAdd(&cnt[threadIdx.x], lc[threadIdx.x]);
}

__global__ void sa_detect_fin(const int* cnt, int* flags) {
  if (threadIdx.x != 0) return;
  flags[0] = (cnt[0] > 1800) ? 1 : 0;
  int mm;
  if (cnt[1] == 0)           mm = (cnt[4] > 0) ? 0 : 1;
  else if (cnt[2] >= cnt[3]) mm = 2;
  else if (cnt[5] == 0)      mm = 3;
  else                       mm = 4;
  flags[1] = mm;
}

// ---------------- mask -> expanded u16 (verified r4) ----------------
__global__ __launch_bounds__(256) void sa_maskexp(const void* mask, u16* m16, const int* flags) {
  int idx = blockIdx.x * 256 + threadIdx.x;
  int i = idx >> 9, c = idx & 511;
  int jw = c >> 5, r = c & 31;
  int g = r >> 3, q = r & 7;
  int t = q >> 2, rr = q & 3;
  long long j = (long long)i * 512 + jw * 32 + t * 16 + 4 * g + rr;
  int mm = flags[1];
  bool v;
  if      (mm == 0) v = ((const int*)mask)[j] != 0;
  else if (mm == 1) v = ((const long long*)mask)[j] != 0;
  else if (mm == 2) v = ((const unsigned char*)mask)[j] != 0;
  else if (mm == 3) v = ((const float*)mask)[j] != 0.0f;
  else              v = ((const unsigned short*)mask)[j] != 0;
  m16[idx] = v ? 0xFFFFu : 0u;
}

// ---------------- hidden -> bf16 pre-swizzled (verified r4/r6) ----------------
__global__ __launch_bounds__(256) void sa_cvt_hs(const void* hs, u16* hsb, const int* flags) {
  int tid = blockIdx.x * 256 + threadIdx.x;
  int row = tid >> 7, u7 = tid & 127;
  int sc = u7 >> 3, u = u7 & 7;
  long long ebase = (long long)row * 1024 + sc * 64 + u * 8;
  s16x8 ov;
  if (flags[0]) {
    ov = *(const s16x8*)((const u16*)hs + ebase);
  } else {
    const float4* pf = (const float4*)((const float*)hs + ebase);
    float4 x0 = pf[0], x1 = pf[1];
    ov[0] = f2b(x0.x); ov[1] = f2b(x0.y); ov[2] = f2b(x0.z); ov[3] = f2b(x0.w);
    ov[4] = f2b(x1.x); ov[5] = f2b(x1.y); ov[6] = f2b(x1.z); ov[7] = f2b(x1.w);
  }
  *(s16x8*)((char*)hsb + (long long)row * 2048 + sc * 128 + ((u ^ (row & 7)) * 16)) = ov;
}

// ---------------- serial W transpose (verified r4/r6, LIVE) ----------------
__global__ __launch_bounds__(256) void sa_wtrans(const void* W, u16* WT, int Nld, const int* flags) {
  int tid = blockIdx.x * 256 + threadIdx.x;
  int nrow = tid >> 7, u7 = tid & 127;
  int sc = u7 >> 3, u = u7 & 7;
  int kb = sc * 64 + u * 8;
  const int fl = flags[0];
  s16x8 ov;
  #pragma unroll
  for (int e = 0; e < 8; ++e) ov[e] = f2b(load_f(W, (long long)(kb + e) * Nld + nrow, fl));
  *(s16x8*)((char*)WT + (long long)nrow * 2048 + sc * 128 + ((u ^ (nrow & 7)) * 16)) = ov;
}

// ---------------- DIAG A: aligned tiled transpose -> scratch ----------------
__global__ __launch_bounds__(256) void sa_wtrans2(const u16* __restrict__ W, u16* __restrict__ WT,
                                                  int Nld, int K) {
  __shared__ __align__(16) u16 T[64 * 64];
  const int tid = threadIdx.x;
  const int n0 = blockIdx.x * 64, k0 = blockIdx.y * 64;
  #pragma unroll
  for (int it = 0; it < 2; ++it) {
    int kk = it * 32 + (tid >> 3), c = tid & 7;
    s16x8 v = *(const s16x8*)(W + (long long)(k0 + kk) * Nld + n0 + c * 8);
    int pc = c ^ (kk & 7) ^ ((kk >> 3) & 7);
    *(s16x8*)(T + kk * 64 + pc * 8) = v;
  }
  __syncthreads();
  #pragma unroll
  for (int it = 0; it < 2; ++it) {
    int nr = it * 32 + (tid >> 3), u = tid & 7;
    s16x8 o;
    #pragma unroll
    for (int e = 0; e < 8; ++e) {
      int k = u * 8 + e;
      int pc = (nr >> 3) ^ (k & 7) ^ ((k >> 3) & 7);
      o[e] = T[k * 64 + pc * 8 + (nr & 7)];
    }
    int nrow = n0 + nr;
    *(s16x8*)((char*)WT + (long long)nrow * (K * 2) + (k0 >> 6) * 128 + ((u ^ (nrow & 7)) * 16)) = o;
  }
}

__global__ __launch_bounds__(256) void sa_cmpA(const u16* __restrict__ A, const u16* __restrict__ B,
                                               int* dbg) {
  long long base = ((long long)blockIdx.x * 256 + threadIdx.x) * 8;
  s16x8 a = *(const s16x8*)(A + base);
  s16x8 b = *(const s16x8*)(B + base);
  int m = 0;
  #pragma unroll
  for (int e = 0; e < 8; ++e) if (a[e] != b[e]) m++;
  if (m) atomicAdd(&dbg[0], m);
}

// ---------------- DIAG B: V[s][d]-epilogue index formula, pattern-filled ----------------
__global__ __launch_bounds__(256) void sa_patfill(u16* Vp) {
  const int tid = threadIdx.x, w = tid >> 6, lane = tid & 63;
  const int g = lane >> 4, li = lane & 15;
  int bx = blockIdx.x, by = blockIdx.y;
  xcd_swz(bx, by);
  const int m0 = by * 128, n0 = bx * 128;
  const int wm = (w >> 1) * 64, wn = (w & 1) * 64;
  const int s0 = (m0 + wm) >> 4;
  #pragma unroll
  for (int nj = 0; nj < 4; ++nj) {
    int colbase = n0 + wn + nj * 16;
    int c16 = colbase >> 4;
    int ht = c16 % 12, n = c16 / 12;
    int colmod = ht * 16 + li;
    if (ht >= 8) {
      int d = colmod - 128;
      #pragma unroll
      for (int rr = 0; rr < 4; ++rr) {
        int b = 4 * g + rr;
        #pragma unroll
        for (int mi = 0; mi < 4; ++mi) {
          int bn = b * 16 + n, s = s0 + mi;
          Vp[(long long)bn * 32768 + s * 64 + d] = hpat(bn, s, d);
        }
      }
    }
  }
}

__global__ __launch_bounds__(256) void sa_chkB(const u16* __restrict__ Vp, int* dbg) {
  long long gid = (long long)blockIdx.x * 256 + threadIdx.x;   // 0..8388607
  int bn = (int)(gid >> 15), s = (int)((gid >> 6) & 511), d = (int)(gid & 63);
  if (Vp[gid] != hpat(bn, s, d)) atomicAdd(&dbg[1], 1);
}

// ---------------- DIAG C: attn5 V-staging swizzle pair over the pattern ----------------
__global__ __launch_bounds__(1024) void sa_stagechkC(const u16* __restrict__ Vp, int* dbg) {
  __shared__ __align__(16) u16 Vs[32768];
  const int tid = threadIdx.x;
  const int bn = blockIdx.y * 16 + blockIdx.x;
  const u16* vg = Vp + (long long)bn * 32768;
  #pragma unroll
  for (int q = 0; q < 4; ++q) {
    int lin = q * 1024 + tid;
    int s = lin >> 3, dc = lin & 7;
    s16x8 v = *(const s16x8*)(vg + s * 64 + dc * 8);
    #pragma unroll
    for (int e = 0; e < 8; ++e) {
      int d = dc * 8 + e;
      Vs[d * 512 + (((s >> 3) ^ e ^ dc) * 8) + (s & 7)] = v[e];
    }
  }
  __syncthreads();
  if (tid < 64) {
    int g = tid >> 4, li = tid & 15;
    int mism = 0;
    for (int jw = 0; jw < 16; ++jw)
      for (int dt = 0; dt < 4; ++dt) {
        int d = dt * 16 + li;
        const u16* p = Vs + d * 512 + (((jw * 4 + g) ^ (d & 7) ^ ((d >> 3) & 7)) * 8);
        #pragma unroll
        for (int j = 0; j < 8; ++j)
          if (p[j] != hpat(bn, (jw * 4 + g) * 8 + j, d)) mism++;
      }
    if (mism) atomicAdd(&dbg[2], mism);
  }
}

// ---------------- named spin markers (distinct kernel names = unambiguous readout) ----------------
__global__ void sa_spinA(const int* dbg, int* sink) {
  if (dbg[0] == 0) return;
  float v = 1.0f;
  for (int i = 0; i < 400000; ++i) v = fmaf(v, 0.9999999f, 1e-9f);
  if (v == 123.456f) *sink = 1;
}
__global__ void sa_spinB(const int* dbg, int* sink) {
  if (dbg[1] == 0) return;
  float v = 1.0f;
  for (int i = 0; i < 400000; ++i) v = fmaf(v, 0.9999999f, 1e-9f);
  if (v == 123.456f) *sink = 1;
}
__global__ void sa_spinC(const int* dbg, int* sink) {
  if (dbg[2] == 0) return;
  float v = 1.0f;
  for (int i = 0; i < 400000; ++i) v = fmaf(v, 0.9999999f, 1e-9f);
  if (v == 123.456f) *sink = 1;
}

// ---------------- MFMA GEMM 1 (verified r4/r6 live) ----------------
__global__ __launch_bounds__(256) void mm_qkv(const u16* __restrict__ Asrc, const u16* __restrict__ BT,
                                              const void* bias, u16* qk, u16* vT, const int* flags) {
  __shared__ u16 As[128 * 64];
  __shared__ u16 Bs[128 * 64];
  const int tid = threadIdx.x, w = tid >> 6, lane = tid & 63;
  const int g = lane >> 4, li = lane & 15;
  int bx = blockIdx.x, by = blockIdx.y;
  xcd_swz(bx, by);
  const int m0 = by * 128, n0 = bx * 128;
  const int wm = (w >> 1) * 64, wn = (w & 1) * 64;
  const int K = 1024;
  f32x4 acc[4][4] = {};
  for (int k0 = 0; k0 < K; k0 += 64) {
    if (k0) __syncthreads();
    #pragma unroll
    for (int q = 0; q < 4; ++q) {
      int c = w * 4 + q;
      int r = c * 8 + (lane >> 3);
      gll16(Asrc + (long long)(m0 + r) * K + k0 + (lane & 7) * 8, &As[c * 512]);
      gll16(BT   + (long long)(n0 + r) * K + k0 + (lane & 7) * 8, &Bs[c * 512]);
    }
    __syncthreads();
    #pragma unroll
    for (int ks = 0; ks < 2; ++ks) {
      s16x8 af[4], bfr[4];
      #pragma unroll
      for (int mi = 0; mi < 4; ++mi) {
        int r = wm + mi * 16 + li;
        int off = (ks * 64 + g * 16) ^ ((r & 7) << 4);
        af[mi] = *(const s16x8*)((const char*)As + r * 128 + off);
      }
      #pragma unroll
      for (int nj = 0; nj < 4; ++nj) {
        int r = wn + nj * 16 + li;
        int off = (ks * 64 + g * 16) ^ ((r & 7) << 4);
        bfr[nj] = *(const s16x8*)((const char*)Bs + r * 128 + off);
      }
      #pragma unroll
      for (int mi = 0; mi < 4; ++mi)
        #pragma unroll
        for (int nj = 0; nj < 4; ++nj)
          acc[mi][nj] = mfma_bf16(af[mi], bfr[nj], acc[mi][nj]);
    }
  }
  const int fl = flags[0];
  const int s0 = (m0 + wm) >> 4;
  #pragma unroll
  for (int nj = 0; nj < 4; ++nj) {
    int colbase = n0 + wn + nj * 16;
    int col = colbase + li;
    float bv = load_f(bias, col, fl);
    int c16 = colbase >> 4;
    int ht = c16 % 12, n = c16 / 12;
    int colmod = (ht * 16) + li;
    if (ht < 8) {
      #pragma unroll
      for (int mi = 0; mi < 4; ++mi) {
        int s = s0 + mi;
        #pragma unroll
        for (int rr = 0; rr < 4; ++rr) {
          int b = 4 * g + rr;
          qk[((long long)(b * 512 + s)) * 2048 + n * 128 + colmod] =
              f2b(acc[mi][nj][rr] + bv);
        }
      }
    } else {
      int d = colmod - 128;
      #pragma unroll
      for (int rr = 0; rr < 4; ++rr) {
        int b = 4 * g + rr;
        u16x4 pk;
        #pragma unroll
        for (int mi = 0; mi < 4; ++mi) pk[mi] = f2b(acc[mi][nj][rr] + bv);
        *(u16x4*)(vT + ((long long)(b * 16 + n)) * 32768 + (long long)d * 512 + s0) = pk;
      }
    }
  }
}

// ---------------- flash attention v4 (verified r4/r6 live, verbatim) ----------------
__global__ __launch_bounds__(1024) void sa_attn4(const u16* __restrict__ qk, const u16* __restrict__ vT,
                                                 const u16* __restrict__ m16, u16* __restrict__ ctx) {
  __shared__ __align__(16) u16 SHM[49152];
  u16* const Vs = SHM;
  u16* const PB = SHM + 32768;

  const int tid = threadIdx.x, w = tid >> 6, lane = tid & 63;
  const int g = lane >> 4, li = lane & 15;
  const int n = blockIdx.x, b = blockIdx.y;

  const u16* vg = vT + (long long)(b * 16 + n) * 32768;
  #pragma unroll
  for (int q = 0; q < 4; ++q) {
    int lin = q * 1024 + tid;
    int d = lin >> 6, c = lin & 63;
    s16x8 v = *(const s16x8*)(vg + (long long)d * 512 + c * 8);
    *(s16x8*)((char*)Vs + d * 1024 + ((c ^ (d & 7)) * 16)) = v;
  }
  __syncthreads();

  const int i0 = w * 32;
  s16x8 qf0[2], qf1[2];
  #pragma unroll
  for (int tl = 0; tl < 2; ++tl) {
    const u16* qb = qk + ((long long)(b * 512 + i0 + tl * 16 + li)) * 2048 + n * 128;
    qf0[tl] = *(const s16x8*)(qb + g * 8);
    qf1[tl] = *(const s16x8*)(qb + 32 + g * 8);
  }
  s16x8 af1;
  #pragma unroll
  for (int e = 0; e < 8; ++e) af1[e] = (li == 0) ? (short)0x3F80 : (short)0;

  char* const pw = (char*)PB + w * 2048;
  const float SC  = 0.125f * 1.44269504f;
  const float THR = 44.3614f;

  const u16* kbase = qk + (long long)(b * 512) * 2048 + n * 128 + 64;
  const u16* mk0 = m16 + (long long)(i0 + li) * 512 + g * 8;
  const u16* mk1 = m16 + (long long)(i0 + 16 + li) * 512 + g * 8;

  f32x4 cacc[2][4] = {};
  f32x4 lacc[2] = {};
  float m[2] = {-1e30f, -1e30f};

  for (int jw = 0; jw < 16; ++jw) {
    uint4 mmv[2];
    mmv[0] = *(const uint4*)(mk0 + jw * 32);
    mmv[1] = *(const uint4*)(mk1 + jw * 32);
    s16x8 kf0[2], kf1[2];
    #pragma unroll
    for (int t = 0; t < 2; ++t) {
      const u16* kb = kbase + (long long)(jw * 32 + t * 16 + li) * 2048;
      kf0[t] = *(const s16x8*)(kb + g * 8);
      kf1[t] = *(const s16x8*)(kb + 32 + g * 8);
    }
    f32x4 sa[2][2];
    #pragma unroll
    for (int tl = 0; tl < 2; ++tl)
      #pragma unroll
      for (int t = 0; t < 2; ++t) {
        f32x4 z = {};
        z = mfma_bf16(kf0[t], qf0[tl], z);
        z = mfma_bf16(kf1[t], qf1[tl], z);
        sa[tl][t] = z;
      }
    s16x8 pf[2];
    #pragma unroll
    for (int tl = 0; tl < 2; ++tl) {
      float pm = fmaxf(fmaxf(fmaxf(sa[tl][0][0], sa[tl][0][1]), fmaxf(sa[tl][0][2], sa[tl][0][3])),
                       fmaxf(fmaxf(sa[tl][1][0], sa[tl][1][1]), fmaxf(sa[tl][1][2], sa[tl][1][3])));
      pm = fmaxf(pm, __shfl_xor(pm, 16));
      pm = fmaxf(pm, __shfl_xor(pm, 32));
      if (__any(pm > m[tl] + THR)) {
        float mn = fmaxf(m[tl], pm);
        float sc = __builtin_exp2f((m[tl] - mn) * SC);
        lacc[tl] *= sc;
        #pragma unroll
        for (int dt = 0; dt < 4; ++dt) cacc[tl][dt] *= sc;
        m[tl] = mn;
      }
      float mv = m[tl];
      float p0 = __builtin_exp2f((sa[tl][0][0] - mv) * SC);
      float p1 = __builtin_exp2f((sa[tl][0][1] - mv) * SC);
      float p2 = __builtin_exp2f((sa[tl][0][2] - mv) * SC);
      float p3 = __builtin_exp2f((sa[tl][0][3] - mv) * SC);
      float p4 = __builtin_exp2f((sa[tl][1][0] - mv) * SC);
      float p5 = __builtin_exp2f((sa[tl][1][1] - mv) * SC);
      float p6 = __builtin_exp2f((sa[tl][1][2] - mv) * SC);
      float p7 = __builtin_exp2f((sa[tl][1][3] - mv) * SC);
      u32 r0 = cvtpk(p0, p1) & mmv[tl].x;
      u32 r1 = cvtpk(p2, p3) & mmv[tl].y;
      u32 r2 = cvtpk(p4, p5) & mmv[tl].z;
      u32 r3 = cvtpk(p6, p7) & mmv[tl].w;
      char* pt = pw + tl * 1024 + li * 64;
      *(uint2*)(pt + ((g ^ (li & 6)) * 8))       = make_uint2(r0, r1);
      *(uint2*)(pt + (((4 + g) ^ (li & 6)) * 8)) = make_uint2(r2, r3);
      pf[tl] = *(const s16x8*)(pw + tl * 1024 + li * 64 + (((2 * g) ^ (li & 6)) * 8));
      lacc[tl] = mfma_bf16(af1, pf[tl], lacc[tl]);
    }
    #pragma unroll
    for (int dt = 0; dt < 4; ++dt) {
      int d = dt * 16 + li;
      s16x8 vf = *(const s16x8*)((const char*)Vs + d * 1024 + (((jw * 4 + g) ^ (d & 7)) * 16));
      #pragma unroll
      for (int tl = 0; tl < 2; ++tl)
        cacc[tl][dt] = mfma_bf16(vf, pf[tl], cacc[tl][dt]);
    }
  }
  #pragma unroll
  for (int tl = 0; tl < 2; ++tl) {
    float lv = __shfl(lacc[tl][0], li);
    float inv = 1.0f / lv;
    #pragma unroll
    for (int dt = 0; dt < 4; ++dt) {
      u32 lo = cvtpk(cacc[tl][dt][0] * inv, cacc[tl][dt][1] * inv);
      u32 hi = cvtpk(cacc[tl][dt][2] * inv, cacc[tl][dt][3] * inv);
      *(uint2*)(pw + li * 128 + (((dt * 4 + g) ^ ((li & 7) << 1)) * 8)) = make_uint2(lo, hi);
    }
    int il = lane >> 2;
    #pragma unroll
    for (int p = 0; p < 2; ++p) {
      int c = (lane & 3) + p * 4;
      s16x8 v = *(const s16x8*)(pw + il * 128 + (((2 * c) ^ ((il & 7) << 1)) * 8));
      *(s16x8*)(ctx + ((long long)((i0 + tl * 16 + il) * 16 + b)) * 1024 + n * 64 +
                ((c ^ (b & 7)) * 8)) = v;
    }
  }
}

// ---------------- MFMA GEMM 2 (verified r4/r6 live) ----------------
__global__ __launch_bounds__(256) void mm_out(const u16* __restrict__ Asrc, const u16* __restrict__ BT,
                                              const void* bias, void* out, const int* flags) {
  __shared__ u16 As[128 * 64];
  __shared__ u16 Bs[128 * 64];
  const int tid = threadIdx.x, w = tid >> 6, lane = tid & 63;
  const int g = lane >> 4, li = lane & 15;
  int bx = blockIdx.x, by = blockIdx.y;
  xcd_swz(bx, by);
  const int m0 = by * 128, n0 = bx * 128;
  const int wm = (w >> 1) * 64, wn = (w & 1) * 64;
  const int K = 1024;
  f32x4 acc[4][4] = {};
  for (int k0 = 0; k0 < K; k0 += 64) {
    if (k0) __syncthreads();
    #pragma unroll
    for (int q = 0; q < 4; ++q) {
      int c = w * 4 + q;
      int r = c * 8 + (lane >> 3);
      gll16(Asrc + (long long)(m0 + r) * K + k0 + (lane & 7) * 8, &As[c * 512]);
      gll16(BT   + (long long)(n0 + r) * K + k0 + (lane & 7) * 8, &Bs[c * 512]);
    }
    __syncthreads();
    #pragma unroll
    for (int ks = 0; ks < 2; ++ks) {
      s16x8 af[4], bfr[4];
      #pragma unroll
      for (int mi = 0; mi < 4; ++mi) {
        int r = wm + mi * 16 + li;
        int off = (ks * 64 + g * 16) ^ ((r & 7) << 4);
        af[mi] = *(const s16x8*)((const char*)As + r * 128 + off);
      }
      #pragma unroll
      for (int nj = 0; nj < 4; ++nj) {
        int r = wn + nj * 16 + li;
        int off = (ks * 64 + g * 16) ^ ((r & 7) << 4);
        bfr[nj] = *(const s16x8*)((const char*)Bs + r * 128 + off);
      }
      #pragma unroll
      for (int mi = 0; mi < 4; ++mi)
        #pragma unroll
        for (int nj = 0; nj < 4; ++nj)
          acc[mi][nj] = mfma_bf16(af[mi], bfr[nj], acc[mi][nj]);
    }
  }
  const int fl = flags[0];
  #pragma unroll
  for (int nj = 0; nj < 4; ++nj) {
    int col = n0 + wn + nj * 16 + li;
    float bv = load_f(bias, col, fl);
    #pragma unroll
    for (int mi = 0; mi < 4; ++mi) {
      #pragma unroll
      for (int rr = 0; rr < 4; ++rr) {
        long long row = m0 + wm + mi * 16 + 4 * g + rr;
        float v = acc[mi][nj][rr] + bv;
        if (fl) ((u16*)out)[row * 1024 + col] = f2b(v);
        else    ((float*)out)[row * 1024 + col] = v;
      }
    }
  }
}

extern "C" void kernel_launch(void* const* d_in, const int* in_sizes, int n_in,
                              void* d_out, int out_size, void* d_ws, size_t ws_size,
                              hipStream_t stream) {
  const void* hs   = d_in[0];
  const void* mask = d_in[1];
  const void* Wqkv = d_in[2];
  const void* bqkv = d_in[3];
  const void* Wout = d_in[4];
  const void* bout = d_in[5];

  char* ws = (char*)d_ws;
  int* flags = (int*)(ws + OFF_FLAGS);
  int* cnt   = (int*)(ws + 64);
  int* dbg   = (int*)(ws + 128);
  int* sink  = (int*)(ws + 192);
  u16* m16   = (u16*)(ws + OFF_M16);
  u16* WqkvT = (u16*)(ws + OFF_WQT);
  u16* WoutT = (u16*)(ws + OFF_WOT);
  u16* qk    = (u16*)(ws + OFF_QK);
  u16* vT    = (u16*)(ws + OFF_VT);
  u16* ctx   = (u16*)(ws + OFF_CTX);
  u16* hsb   = ctx;                                  // aliased; hsb dead before ctx written
  u16* WT2   = (u16*)(ws + OFF_QK);                  // diag scratch in qk region (6MB)
  u16* Vp    = (u16*)(ws + OFF_QK + 8388608);        // diag scratch in qk region (16MB)

  hipMemsetAsync(ws + 64, 0, 192, stream);
  sa_detect_part<<<64, 256, 0, stream>>>(hs, mask, cnt);
  sa_detect_fin<<<1, 64, 0, stream>>>(cnt, flags);
  sa_maskexp<<<1024, 256, 0, stream>>>(mask, m16, flags);
  sa_cvt_hs<<<(ROWS * 128) / 256, 256, 0, stream>>>(hs, hsb, flags);
  sa_wtrans<<<(QKVC * 128) / 256, 256, 0, stream>>>(Wqkv, WqkvT, QKVC, flags);
  sa_wtrans<<<(HH * 128) / 256, 256, 0, stream>>>(Wout, WoutT, HH, flags);

  // ---- diagnostics (scratch lives in qk region; runs before mm_qkv overwrites it) ----
  sa_wtrans2<<<dim3(QKVC / 64, HH / 64), 256, 0, stream>>>((const u16*)Wqkv, WT2, QKVC, HH);
  sa_cmpA<<<(QKVC * HH) / (256 * 8), 256, 0, stream>>>(WT2, WqkvT, dbg);
  sa_patfill<<<dim3(QKVC / 128, ROWS / 128), 256, 0, stream>>>(Vp);
  sa_chkB<<<(256 * 32768) / 256, 256, 0, stream>>>(Vp, dbg);
  sa_stagechkC<<<dim3(16, 16), 1024, 0, stream>>>(Vp, dbg);
  sa_spinA<<<1, 64, 0, stream>>>(dbg, sink);
  sa_spinB<<<1, 64, 0, stream>>>(dbg, sink);
  sa_spinC<<<1, 64, 0, stream>>>(dbg, sink);

  // ---- live pipeline (r6-green, verbatim) ----
  mm_qkv<<<dim3(QKVC / 128, ROWS / 128), 256, 0, stream>>>(hsb, WqkvT, bqkv, qk, vT, flags);
  sa_attn4<<<dim3(NHEAD, BB), 1024, 0, stream>>>(qk, vT, m16, ctx);
  mm_out<<<dim3(HH / 128, ROWS / 128), 256, 0, stream>>>(ctx, WoutT, bout, d_out, flags);
}

// Round 9
// 210.957 us; speedup vs baseline: 13.2162x; 6.1442x over previous
//
#include <hip/hip_runtime.h>
#include <hip/hip_bf16.h>

typedef __hip_bfloat16 bf16;
typedef unsigned short u16;
typedef unsigned int u32;
typedef unsigned long long u64;
typedef float f32x4 __attribute__((ext_vector_type(4)));
typedef short s16x8 __attribute__((ext_vector_type(8)));
typedef unsigned short u16x4 __attribute__((ext_vector_type(4)));

static constexpr int SQ    = 512;
static constexpr int BB    = 16;
static constexpr int HH    = 1024;
static constexpr int NHEAD = 16;
static constexpr int ROWS  = SQ * BB;        // 8192
static constexpr int QKVC  = 3 * HH;         // 3072

// ---- ws layout (bytes) ----
static constexpr long long OFF_FLAGS = 0;        // flags; cnt at +64
static constexpr long long OFF_M16   = 4096;     // 512KB expanded mask
static constexpr long long OFF_WQT   = 1048576;
static constexpr long long OFF_WOT   = OFF_WQT + (long long)QKVC * HH * 2;
static constexpr long long OFF_QK    = OFF_WOT + (long long)HH * HH * 2;
static constexpr long long OFF_VT    = OFF_QK + (long long)ROWS * 2048 * 2;
static constexpr long long OFF_CTX   = OFF_VT + (long long)256 * 64 * 512 * 2;

__device__ __forceinline__ float load_f(const void* p, long long i, int is_bf16) {
  if (is_bf16) return __bfloat162float(((const bf16*)p)[i]);
  return ((const float*)p)[i];
}
__device__ __forceinline__ u16 f2b(float x) { bf16 h = __float2bfloat16(x); return *(u16*)&h; }
__device__ __forceinline__ f32x4 mfma_bf16(s16x8 a, s16x8 b, f32x4 c) {
  return __builtin_amdgcn_mfma_f32_16x16x32_bf16(a, b, c, 0, 0, 0);
}
__device__ __forceinline__ void gll16(const void* g, void* lds) {
  __builtin_amdgcn_global_load_lds((const __attribute__((address_space(1))) unsigned int*)g,
                                   (__attribute__((address_space(3))) unsigned int*)lds, 16, 0, 0);
}
__device__ __forceinline__ u32 cvtpk(float lo, float hi) {
  u32 r;
  asm volatile("v_cvt_pk_bf16_f32 %0, %1, %2" : "=v"(r) : "v"(lo), "v"(hi));
  return r;
}
// bijective XCD-aware block swizzle (live-verified r6/r8)
__device__ __forceinline__ void xcd_swz(int& bx, int& by) {
  int gx = gridDim.x;
  int nw = gx * gridDim.y;
  int lin = by * gx + bx;
  int q = nw >> 3;
  int nl = (lin & 7) * q + (lin >> 3);
  bx = nl % gx;
  by = nl / gx;
}

// ---------------- dtype detection (verified r1-r8, verbatim) ----------------
__global__ __launch_bounds__(256) void sa_detect_part(const void* hs, const void* mask, int* cnt) {
  __shared__ int lc[6];
  if (threadIdx.x < 6) lc[threadIdx.x] = 0;
  __syncthreads();
  int gid = blockIdx.x * 256 + threadIdx.x;
  if (gid < 2048) {
    unsigned short v = ((const unsigned short*)hs)[2 * gid];
    float f = __uint_as_float(((unsigned)v) << 16);
    float a = fabsf(f);
    if (v == 0 || (a > 1e-9f && a < 1e4f)) atomicAdd(&lc[0], 1);
  }
  const unsigned char* mb = (const unsigned char*)mask;
  int codd = 0, c1 = 0, c3f = 0, c48 = 0, cb1 = 0;
  #pragma unroll
  for (int r = 0; r < 4; ++r) {
    int i = gid * 4 + r;
    int base = i * 4;
    unsigned char b1 = mb[base + 1], b3 = mb[base + 3];
    if (b1 | b3) codd++;
    if (b1) cb1++;
    if (b1 == 1) c1++;
    if (b3 == 1) c1++;
    if (b1 == 0x3f) c3f++;
    if (b3 == 0x3f) c3f++;
    if (i & 1) { if (mb[base]) c48++; }
  }
  atomicAdd(&lc[1], codd);
  atomicAdd(&lc[2], c1);
  atomicAdd(&lc[3], c3f);
  atomicAdd(&lc[4], c48);
  atomicAdd(&lc[5], cb1);
  __syncthreads();
  if (threadIdx.x < 6) atomicAdd(&cnt[threadIdx.x], lc[threadIdx.x]);
}

__global__ void sa_detect_fin(const int* cnt, int* flags) {
  if (threadIdx.x != 0) return;
  flags[0] = (cnt[0] > 1800) ? 1 : 0;
  int mm;
  if (cnt[1] == 0)           mm = (cnt[4] > 0) ? 0 : 1;
  else if (cnt[2] >= cnt[3]) mm = 2;
  else if (cnt[5] == 0)      mm = 3;
  else                       mm = 4;
  flags[1] = mm;
}

// ---------------- mask -> expanded u16 (verified r4+) ----------------
__global__ __launch_bounds__(256) void sa_maskexp(const void* mask, u16* m16, const int* flags) {
  int idx = blockIdx.x * 256 + threadIdx.x;
  int i = idx >> 9, c = idx & 511;
  int jw = c >> 5, r = c & 31;
  int g = r >> 3, q = r & 7;
  int t = q >> 2, rr = q & 3;
  long long j = (long long)i * 512 + jw * 32 + t * 16 + 4 * g + rr;
  int mm = flags[1];
  bool v;
  if      (mm == 0) v = ((const int*)mask)[j] != 0;
  else if (mm == 1) v = ((const long long*)mask)[j] != 0;
  else if (mm == 2) v = ((const unsigned char*)mask)[j] != 0;
  else if (mm == 3) v = ((const float*)mask)[j] != 0.0f;
  else              v = ((const unsigned short*)mask)[j] != 0;
  m16[idx] = v ? 0xFFFFu : 0u;
}

// ---------------- hidden -> bf16 pre-swizzled (verified r4+) ----------------
__global__ __launch_bounds__(256) void sa_cvt_hs(const void* hs, u16* hsb, const int* flags) {
  int tid = blockIdx.x * 256 + threadIdx.x;
  int row = tid >> 7, u7 = tid & 127;
  int sc = u7 >> 3, u = u7 & 7;
  long long ebase = (long long)row * 1024 + sc * 64 + u * 8;
  s16x8 ov;
  if (flags[0]) {
    ov = *(const s16x8*)((const u16*)hs + ebase);
  } else {
    const float4* pf = (const float4*)((const float*)hs + ebase);
    float4 x0 = pf[0], x1 = pf[1];
    ov[0] = f2b(x0.x); ov[1] = f2b(x0.y); ov[2] = f2b(x0.z); ov[3] = f2b(x0.w);
    ov[4] = f2b(x1.x); ov[5] = f2b(x1.y); ov[6] = f2b(x1.z); ov[7] = f2b(x1.w);
  }
  *(s16x8*)((char*)hsb + (long long)row * 2048 + sc * 128 + ((u ^ (row & 7)) * 16)) = ov;
}

// ---------------- serial W transpose (live-verified r4/r6/r8; tiled version is BROKEN, do not use) ----------------
__global__ __launch_bounds__(256) void sa_wtrans(const void* W, u16* WT, int Nld, const int* flags) {
  int tid = blockIdx.x * 256 + threadIdx.x;
  int nrow = tid >> 7, u7 = tid & 127;
  int sc = u7 >> 3, u = u7 & 7;
  int kb = sc * 64 + u * 8;
  const int fl = flags[0];
  s16x8 ov;
  #pragma unroll
  for (int e = 0; e < 8; ++e) ov[e] = f2b(load_f(W, (long long)(kb + e) * Nld + nrow, fl));
  *(s16x8*)((char*)WT + (long long)nrow * 2048 + sc * 128 + ((u ^ (nrow & 7)) * 16)) = ov;
}

// ---------------- MFMA GEMM 1: hsb @ WqkvT -> qk + V[s][d]  (V-epilogue bit-verified, diag B r8) ----------------
__global__ __launch_bounds__(256) void mm_qkv(const u16* __restrict__ Asrc, const u16* __restrict__ BT,
                                              const void* bias, u16* qk, u16* V, const int* flags) {
  __shared__ u16 As[128 * 64];
  __shared__ u16 Bs[128 * 64];
  const int tid = threadIdx.x, w = tid >> 6, lane = tid & 63;
  const int g = lane >> 4, li = lane & 15;
  int bx = blockIdx.x, by = blockIdx.y;
  xcd_swz(bx, by);
  const int m0 = by * 128, n0 = bx * 128;
  const int wm = (w >> 1) * 64, wn = (w & 1) * 64;
  const int K = 1024;
  f32x4 acc[4][4] = {};
  for (int k0 = 0; k0 < K; k0 += 64) {
    if (k0) __syncthreads();
    #pragma unroll
    for (int q = 0; q < 4; ++q) {
      int c = w * 4 + q;
      int r = c * 8 + (lane >> 3);
      gll16(Asrc + (long long)(m0 + r) * K + k0 + (lane & 7) * 8, &As[c * 512]);
      gll16(BT   + (long long)(n0 + r) * K + k0 + (lane & 7) * 8, &Bs[c * 512]);
    }
    __syncthreads();
    #pragma unroll
    for (int ks = 0; ks < 2; ++ks) {
      s16x8 af[4], bfr[4];
      #pragma unroll
      for (int mi = 0; mi < 4; ++mi) {
        int r = wm + mi * 16 + li;
        int off = (ks * 64 + g * 16) ^ ((r & 7) << 4);
        af[mi] = *(const s16x8*)((const char*)As + r * 128 + off);
      }
      #pragma unroll
      for (int nj = 0; nj < 4; ++nj) {
        int r = wn + nj * 16 + li;
        int off = (ks * 64 + g * 16) ^ ((r & 7) << 4);
        bfr[nj] = *(const s16x8*)((const char*)Bs + r * 128 + off);
      }
      #pragma unroll
      for (int mi = 0; mi < 4; ++mi)
        #pragma unroll
        for (int nj = 0; nj < 4; ++nj)
          acc[mi][nj] = mfma_bf16(af[mi], bfr[nj], acc[mi][nj]);
    }
  }
  const int fl = flags[0];
  const int s0 = (m0 + wm) >> 4;
  #pragma unroll
  for (int nj = 0; nj < 4; ++nj) {
    int colbase = n0 + wn + nj * 16;
    int col = colbase + li;
    float bv = load_f(bias, col, fl);
    int c16 = colbase >> 4;
    int ht = c16 % 12, n = c16 / 12;
    int colmod = (ht * 16) + li;
    if (ht < 8) {
      // q/k -> qk[b*512+s][n*128 + colmod]  (32B-aligned 32B runs)
      #pragma unroll
      for (int mi = 0; mi < 4; ++mi) {
        int s = s0 + mi;
        #pragma unroll
        for (int rr = 0; rr < 4; ++rr) {
          int b = 4 * g + rr;
          qk[((long long)(b * 512 + s)) * 2048 + n * 128 + colmod] =
              f2b(acc[mi][nj][rr] + bv);
        }
      }
    } else {
      // v -> V[(b*16+n)][s][d]  (plain rows, 32B runs; index formula = diag-B-verified)
      int d = colmod - 128;
      #pragma unroll
      for (int rr = 0; rr < 4; ++rr) {
        int b = 4 * g + rr;
        #pragma unroll
        for (int mi = 0; mi < 4; ++mi)
          V[((long long)(b * 16 + n)) * 32768 + (s0 + mi) * 64 + d] =
              f2b(acc[mi][nj][rr] + bv);
      }
    }
  }
}

// ---------------- flash attention v5: V[s][d] -> in-LDS transpose (swizzle pair bit-verified, diag C r8) ----------------
__global__ __launch_bounds__(1024) void sa_attn5(const u16* __restrict__ qk, const u16* __restrict__ V,
                                                 const u16* __restrict__ m16, u16* __restrict__ ctx) {
  __shared__ __align__(16) u16 SHM[49152];    // Vs 64KB + P 32KB
  u16* const Vs = SHM;                         // [64 d][64 s-chunks of 8], pc = c ^ (d&7) ^ ((d>>3)&7)
  u16* const PB = SHM + 32768;

  const int tid = threadIdx.x, w = tid >> 6, lane = tid & 63;
  const int g = lane >> 4, li = lane & 15;
  const int n = blockIdx.x, b = blockIdx.y;

  // ---- stage V with in-LDS transpose (coalesced row reads; scalar swizzled writes) ----
  const u16* vg = V + (long long)(b * 16 + n) * 32768;
  #pragma unroll
  for (int q = 0; q < 4; ++q) {
    int lin = q * 1024 + tid;
    int s = lin >> 3, dc = lin & 7;
    s16x8 v = *(const s16x8*)(vg + s * 64 + dc * 8);
    #pragma unroll
    for (int e = 0; e < 8; ++e) {
      int d = dc * 8 + e;
      Vs[d * 512 + (((s >> 3) ^ e ^ dc) * 8) + (s & 7)] = v[e];
    }
  }
  __syncthreads();

  const int i0 = w * 32;
  s16x8 qf0[2], qf1[2];
  #pragma unroll
  for (int tl = 0; tl < 2; ++tl) {
    const u16* qb = qk + ((long long)(b * 512 + i0 + tl * 16 + li)) * 2048 + n * 128;
    qf0[tl] = *(const s16x8*)(qb + g * 8);
    qf1[tl] = *(const s16x8*)(qb + 32 + g * 8);
  }
  s16x8 af1;
  #pragma unroll
  for (int e = 0; e < 8; ++e) af1[e] = (li == 0) ? (short)0x3F80 : (short)0;

  char* const pw = (char*)PB + w * 2048;
  const float SC  = 0.125f * 1.44269504f;
  const float THR = 44.3614f;

  const u16* kbase = qk + (long long)(b * 512) * 2048 + n * 128 + 64;
  const u16* mk0 = m16 + (long long)(i0 + li) * 512 + g * 8;
  const u16* mk1 = m16 + (long long)(i0 + 16 + li) * 512 + g * 8;

  f32x4 cacc[2][4] = {};
  f32x4 lacc[2] = {};
  float m[2] = {-1e30f, -1e30f};

  for (int jw = 0; jw < 16; ++jw) {
    uint4 mmv[2];
    mmv[0] = *(const uint4*)(mk0 + jw * 32);
    mmv[1] = *(const uint4*)(mk1 + jw * 32);
    s16x8 kf0[2], kf1[2];
    #pragma unroll
    for (int t = 0; t < 2; ++t) {
      const u16* kb = kbase + (long long)(jw * 32 + t * 16 + li) * 2048;
      kf0[t] = *(const s16x8*)(kb + g * 8);
      kf1[t] = *(const s16x8*)(kb + 32 + g * 8);
    }
    f32x4 sa[2][2];
    #pragma unroll
    for (int tl = 0; tl < 2; ++tl)
      #pragma unroll
      for (int t = 0; t < 2; ++t) {
        f32x4 z = {};
        z = mfma_bf16(kf0[t], qf0[tl], z);
        z = mfma_bf16(kf1[t], qf1[tl], z);
        sa[tl][t] = z;
      }
    s16x8 pf[2];
    #pragma unroll
    for (int tl = 0; tl < 2; ++tl) {
      float pm = fmaxf(fmaxf(fmaxf(sa[tl][0][0], sa[tl][0][1]), fmaxf(sa[tl][0][2], sa[tl][0][3])),
                       fmaxf(fmaxf(sa[tl][1][0], sa[tl][1][1]), fmaxf(sa[tl][1][2], sa[tl][1][3])));
      pm = fmaxf(pm, __shfl_xor(pm, 16));
      pm = fmaxf(pm, __shfl_xor(pm, 32));
      if (__any(pm > m[tl] + THR)) {
        float mn = fmaxf(m[tl], pm);
        float sc = __builtin_exp2f((m[tl] - mn) * SC);
        lacc[tl] *= sc;
        #pragma unroll
        for (int dt = 0; dt < 4; ++dt) cacc[tl][dt] *= sc;
        m[tl] = mn;
      }
      float mv = m[tl];
      float p0 = __builtin_exp2f((sa[tl][0][0] - mv) * SC);
      float p1 = __builtin_exp2f((sa[tl][0][1] - mv) * SC);
      float p2 = __builtin_exp2f((sa[tl][0][2] - mv) * SC);
      float p3 = __builtin_exp2f((sa[tl][0][3] - mv) * SC);
      float p4 = __builtin_exp2f((sa[tl][1][0] - mv) * SC);
      float p5 = __builtin_exp2f((sa[tl][1][1] - mv) * SC);
      float p6 = __builtin_exp2f((sa[tl][1][2] - mv) * SC);
      float p7 = __builtin_exp2f((sa[tl][1][3] - mv) * SC);
      u32 r0 = cvtpk(p0, p1) & mmv[tl].x;
      u32 r1 = cvtpk(p2, p3) & mmv[tl].y;
      u32 r2 = cvtpk(p4, p5) & mmv[tl].z;
      u32 r3 = cvtpk(p6, p7) & mmv[tl].w;
      char* pt = pw + tl * 1024 + li * 64;
      *(uint2*)(pt + ((g ^ (li & 6)) * 8))       = make_uint2(r0, r1);
      *(uint2*)(pt + (((4 + g) ^ (li & 6)) * 8)) = make_uint2(r2, r3);
      pf[tl] = *(const s16x8*)(pw + tl * 1024 + li * 64 + (((2 * g) ^ (li & 6)) * 8));
      lacc[tl] = mfma_bf16(af1, pf[tl], lacc[tl]);
    }
    #pragma unroll
    for (int dt = 0; dt < 4; ++dt) {
      int d = dt * 16 + li;
      s16x8 vf = *(const s16x8*)(Vs + d * 512 +
                                 (((jw * 4 + g) ^ (d & 7) ^ ((d >> 3) & 7)) * 8));
      #pragma unroll
      for (int tl = 0; tl < 2; ++tl)
        cacc[tl][dt] = mfma_bf16(vf, pf[tl], cacc[tl][dt]);
    }
  }
  #pragma unroll
  for (int tl = 0; tl < 2; ++tl) {
    float lv = __shfl(lacc[tl][0], li);
    float inv = 1.0f / lv;
    #pragma unroll
    for (int dt = 0; dt < 4; ++dt) {
      u32 lo = cvtpk(cacc[tl][dt][0] * inv, cacc[tl][dt][1] * inv);
      u32 hi = cvtpk(cacc[tl][dt][2] * inv, cacc[tl][dt][3] * inv);
      *(uint2*)(pw + li * 128 + (((dt * 4 + g) ^ ((li & 7) << 1)) * 8)) = make_uint2(lo, hi);
    }
    int il = lane >> 2;
    #pragma unroll
    for (int p = 0; p < 2; ++p) {
      int c = (lane & 3) + p * 4;
      s16x8 v = *(const s16x8*)(pw + il * 128 + (((2 * c) ^ ((il & 7) << 1)) * 8));
      *(s16x8*)(ctx + ((long long)((i0 + tl * 16 + il) * 16 + b)) * 1024 + n * 64 +
                ((c ^ (b & 7)) * 8)) = v;
    }
  }
}

// ---------------- MFMA GEMM 2 (live-verified r4/r6/r8) ----------------
__global__ __launch_bounds__(256) void mm_out(const u16* __restrict__ Asrc, const u16* __restrict__ BT,
                                              const void* bias, void* out, const int* flags) {
  __shared__ u16 As[128 * 64];
  __shared__ u16 Bs[128 * 64];
  const int tid = threadIdx.x, w = tid >> 6, lane = tid & 63;
  const int g = lane >> 4, li = lane & 15;
  int bx = blockIdx.x, by = blockIdx.y;
  xcd_swz(bx, by);
  const int m0 = by * 128, n0 = bx * 128;
  const int wm = (w >> 1) * 64, wn = (w & 1) * 64;
  const int K = 1024;
  f32x4 acc[4][4] = {};
  for (int k0 = 0; k0 < K; k0 += 64) {
    if (k0) __syncthreads();
    #pragma unroll
    for (int q = 0; q < 4; ++q) {
      int c = w * 4 + q;
      int r = c * 8 + (lane >> 3);
      gll16(Asrc + (long long)(m0 + r) * K + k0 + (lane & 7) * 8, &As[c * 512]);
      gll16(BT   + (long long)(n0 + r) * K + k0 + (lane & 7) * 8, &Bs[c * 512]);
    }
    __syncthreads();
    #pragma unroll
    for (int ks = 0; ks < 2; ++ks) {
      s16x8 af[4], bfr[4];
      #pragma unroll
      for (int mi = 0; mi < 4; ++mi) {
        int r = wm + mi * 16 + li;
        int off = (ks * 64 + g * 16) ^ ((r & 7) << 4);
        af[mi] = *(const s16x8*)((const char*)As + r * 128 + off);
      }
      #pragma unroll
      for (int nj = 0; nj < 4; ++nj) {
        int r = wn + nj * 16 + li;
        int off = (ks * 64 + g * 16) ^ ((r & 7) << 4);
        bfr[nj] = *(const s16x8*)((const char*)Bs + r * 128 + off);
      }
      #pragma unroll
      for (int mi = 0; mi < 4; ++mi)
        #pragma unroll
        for (int nj = 0; nj < 4; ++nj)
          acc[mi][nj] = mfma_bf16(af[mi], bfr[nj], acc[mi][nj]);
    }
  }
  const int fl = flags[0];
  #pragma unroll
  for (int nj = 0; nj < 4; ++nj) {
    int col = n0 + wn + nj * 16 + li;
    float bv = load_f(bias, col, fl);
    #pragma unroll
    for (int mi = 0; mi < 4; ++mi) {
      #pragma unroll
      for (int rr = 0; rr < 4; ++rr) {
        long long row = m0 + wm + mi * 16 + 4 * g + rr;
        float v = acc[mi][nj][rr] + bv;
        if (fl) ((u16*)out)[row * 1024 + col] = f2b(v);
        else    ((float*)out)[row * 1024 + col] = v;
      }
    }
  }
}

extern "C" void kernel_launch(void* const* d_in, const int* in_sizes, int n_in,
                              void* d_out, int out_size, void* d_ws, size_t ws_size,
                              hipStream_t stream) {
  const void* hs   = d_in[0];
  const void* mask = d_in[1];
  const void* Wqkv = d_in[2];
  const void* bqkv = d_in[3];
  const void* Wout = d_in[4];
  const void* bout = d_in[5];

  char* ws = (char*)d_ws;
  int* flags = (int*)(ws + OFF_FLAGS);
  int* cnt   = (int*)(ws + 64);
  u16* m16   = (u16*)(ws + OFF_M16);
  u16* WqkvT = (u16*)(ws + OFF_WQT);
  u16* WoutT = (u16*)(ws + OFF_WOT);
  u16* qk    = (u16*)(ws + OFF_QK);
  u16* V     = (u16*)(ws + OFF_VT);
  u16* ctx   = (u16*)(ws + OFF_CTX);
  u16* hsb   = ctx;   // aliased; hsb dead before ctx written

  hipMemsetAsync(cnt, 0, 64, stream);
  sa_detect_part<<<64, 256, 0, stream>>>(hs, mask, cnt);
  sa_detect_fin<<<1, 64, 0, stream>>>(cnt, flags);
  sa_maskexp<<<1024, 256, 0, stream>>>(mask, m16, flags);
  sa_cvt_hs<<<(ROWS * 128) / 256, 256, 0, stream>>>(hs, hsb, flags);
  sa_wtrans<<<(QKVC * 128) / 256, 256, 0, stream>>>(Wqkv, WqkvT, QKVC, flags);
  sa_wtrans<<<(HH * 128) / 256, 256, 0, stream>>>(Wout, WoutT, HH, flags);

  mm_qkv<<<dim3(QKVC / 128, ROWS / 128), 256, 0, stream>>>(hsb, WqkvT, bqkv, qk, V, flags);
  sa_attn5<<<dim3(NHEAD, BB), 1024, 0, stream>>>(qk, V, m16, ctx);
  mm_out<<<dim3(HH / 128, ROWS / 128), 256, 0, stream>>>(ctx, WoutT, bout, d_out, flags);
}